// Round 1
// baseline (305.424 us; speedup 1.0000x reference)
//
#include <hip/hip_runtime.h>
#include <hip/hip_bf16.h>
#include <cstdint>
#include <cstddef>

// Problem constants
#define B_N 8192
#define D_K 1024
#define H_N 400
#define K2_N 512
#define E_N 16
#define L_N 256
#define TM 64
#define PAD_ROWS (B_N + E_N * TM)   // 9216 (each expert group padded to TM)
#define NTILES (PAD_ROWS / TM)      // 144

// ---------------- Kernel 0: group samples by expert ----------------
__global__ __launch_bounds__(256) void group_kernel(const int* __restrict__ idx,
                                                    int* __restrict__ off_al,
                                                    int* __restrict__ order) {
  __shared__ int cnt[E_N];
  __shared__ int base[E_N + 1];
  __shared__ int cur[E_N];
  int t = threadIdx.x;
  if (t < E_N) cnt[t] = 0;
  __syncthreads();
  for (int b = t; b < B_N; b += 256) atomicAdd(&cnt[idx[b]], 1);
  __syncthreads();
  if (t == 0) {
    int acc = 0;
    for (int e = 0; e < E_N; ++e) {
      base[e] = acc;
      acc += ((cnt[e] + TM - 1) / TM) * TM;   // pad each group to TM rows
    }
    base[E_N] = acc;
  }
  __syncthreads();
  if (t < E_N) cur[t] = base[t];
  if (t <= E_N) off_al[t] = base[t];
  for (int i = t; i < PAD_ROWS; i += 256) order[i] = -1;
  __syncthreads();
  for (int b = t; b < B_N; b += 256) {
    int e = idx[b];
    int p = atomicAdd(&cur[e], 1);
    order[p] = b;  // slot within this expert's padded segment
  }
}

// ---------------- Kernel 1: h1 = relu(Xg @ W1[e] + b1[e]) ----------------
// Tiles: 64 rows x 64 cols, BK=16. Rows gathered via order[]; output stored
// permuted (row = padded-order index) so GEMM2 reads contiguously.
__global__ __launch_bounds__(256) void gemm1_kernel(const float* __restrict__ x,
                                                    const float* __restrict__ W1,
                                                    const float* __restrict__ b1,
                                                    const int* __restrict__ off_al,
                                                    const int* __restrict__ order,
                                                    float* __restrict__ h1buf) {
  __shared__ int offs[E_N + 1];
  __shared__ int rowidx[TM];
  __shared__ float Xs[16][68];   // [k][m], padded row (68 floats = 17x16B)
  __shared__ float Ws[16][64];   // [k][n]
  const int tid = threadIdx.x;
  const int m0 = blockIdx.x * TM;
  const int n0 = blockIdx.y * 64;
  if (tid <= E_N) offs[tid] = off_al[tid];
  if (tid < TM) rowidx[tid] = order[m0 + tid];
  __syncthreads();
  const int total = offs[E_N];
  if (m0 >= total) return;   // uniform exit
  int e = 0;
  while (m0 >= offs[e + 1]) ++e;

  const int tx = tid & 15, ty = tid >> 4;
  const int sm = tid >> 2, skq = (tid & 3) << 2;     // X staging: row, k-quad
  const int srow = rowidx[sm];
  const int swk = tid >> 4, swn = (tid & 15) << 2;   // W staging: k, n-quad
  const float* W1e = W1 + (size_t)e * D_K * H_N;

  float acc[4][4] = {};
  for (int k0 = 0; k0 < D_K; k0 += 16) {
    float4 v = make_float4(0.f, 0.f, 0.f, 0.f);
    if (srow >= 0) v = *(const float4*)(x + (size_t)srow * D_K + k0 + skq);
    Xs[skq + 0][sm] = v.x; Xs[skq + 1][sm] = v.y;
    Xs[skq + 2][sm] = v.z; Xs[skq + 3][sm] = v.w;
    float4 w = make_float4(0.f, 0.f, 0.f, 0.f);
    const int n = n0 + swn;
    if (n <= H_N - 4) w = *(const float4*)(W1e + (size_t)(k0 + swk) * H_N + n);
    *(float4*)&Ws[swk][swn] = w;
    __syncthreads();
#pragma unroll
    for (int k = 0; k < 16; ++k) {
      const float a0 = Xs[k][ty * 4 + 0], a1 = Xs[k][ty * 4 + 1];
      const float a2 = Xs[k][ty * 4 + 2], a3 = Xs[k][ty * 4 + 3];
      const float c0 = Ws[k][tx * 4 + 0], c1 = Ws[k][tx * 4 + 1];
      const float c2 = Ws[k][tx * 4 + 2], c3 = Ws[k][tx * 4 + 3];
      acc[0][0] += a0 * c0; acc[0][1] += a0 * c1; acc[0][2] += a0 * c2; acc[0][3] += a0 * c3;
      acc[1][0] += a1 * c0; acc[1][1] += a1 * c1; acc[1][2] += a1 * c2; acc[1][3] += a1 * c3;
      acc[2][0] += a2 * c0; acc[2][1] += a2 * c1; acc[2][2] += a2 * c2; acc[2][3] += a2 * c3;
      acc[3][0] += a3 * c0; acc[3][1] += a3 * c1; acc[3][2] += a3 * c2; acc[3][3] += a3 * c3;
    }
    __syncthreads();
  }
#pragma unroll
  for (int i = 0; i < 4; ++i) {
    const int r = ty * 4 + i;
#pragma unroll
    for (int j = 0; j < 4; ++j) {
      const int n = n0 + tx * 4 + j;
      if (n < H_N) {
        float v = acc[i][j] + b1[e * H_N + n];
        h1buf[(size_t)(m0 + r) * H_N + n] = fmaxf(v, 0.f);
      }
    }
  }
}

// ---------------- Kernel 2: out = h1 @ W2[e] + b2[e], scatter ----------------
__global__ __launch_bounds__(256) void gemm2_kernel(const float* __restrict__ h1buf,
                                                    const float* __restrict__ W2,
                                                    const float* __restrict__ b2,
                                                    const int* __restrict__ off_al,
                                                    const int* __restrict__ order,
                                                    float* __restrict__ out) {
  __shared__ int offs[E_N + 1];
  __shared__ int rowidx[TM];
  __shared__ float Xs[16][68];
  __shared__ float Ws[16][64];
  const int tid = threadIdx.x;
  const int m0 = blockIdx.x * TM;
  const int n0 = blockIdx.y * 64;
  if (tid <= E_N) offs[tid] = off_al[tid];
  if (tid < TM) rowidx[tid] = order[m0 + tid];
  __syncthreads();
  const int total = offs[E_N];
  if (m0 >= total) return;
  int e = 0;
  while (m0 >= offs[e + 1]) ++e;

  const int tx = tid & 15, ty = tid >> 4;
  const int sm = tid >> 2, skq = (tid & 3) << 2;
  const int swk = tid >> 4, swn = (tid & 15) << 2;
  const float* W2e = W2 + (size_t)e * H_N * K2_N;

  float acc[4][4] = {};
  for (int k0 = 0; k0 < H_N; k0 += 16) {   // 400/16 = 25 exact
    float4 v = *(const float4*)(h1buf + (size_t)(m0 + sm) * H_N + k0 + skq);
    Xs[skq + 0][sm] = v.x; Xs[skq + 1][sm] = v.y;
    Xs[skq + 2][sm] = v.z; Xs[skq + 3][sm] = v.w;
    float4 w = *(const float4*)(W2e + (size_t)(k0 + swk) * K2_N + n0 + swn);
    *(float4*)&Ws[swk][swn] = w;
    __syncthreads();
#pragma unroll
    for (int k = 0; k < 16; ++k) {
      const float a0 = Xs[k][ty * 4 + 0], a1 = Xs[k][ty * 4 + 1];
      const float a2 = Xs[k][ty * 4 + 2], a3 = Xs[k][ty * 4 + 3];
      const float c0 = Ws[k][tx * 4 + 0], c1 = Ws[k][tx * 4 + 1];
      const float c2 = Ws[k][tx * 4 + 2], c3 = Ws[k][tx * 4 + 3];
      acc[0][0] += a0 * c0; acc[0][1] += a0 * c1; acc[0][2] += a0 * c2; acc[0][3] += a0 * c3;
      acc[1][0] += a1 * c0; acc[1][1] += a1 * c1; acc[1][2] += a1 * c2; acc[1][3] += a1 * c3;
      acc[2][0] += a2 * c0; acc[2][1] += a2 * c1; acc[2][2] += a2 * c2; acc[2][3] += a2 * c3;
      acc[3][0] += a3 * c0; acc[3][1] += a3 * c1; acc[3][2] += a3 * c2; acc[3][3] += a3 * c3;
    }
    __syncthreads();
  }
#pragma unroll
  for (int i = 0; i < 4; ++i) {
    const int r = ty * 4 + i;
    const int s = rowidx[r];
    if (s < 0) continue;   // padding row
#pragma unroll
    for (int j = 0; j < 4; ++j) {
      const int n = n0 + tx * 4 + j;
      const float v = acc[i][j] + b2[e * K2_N + n];
      if (n < L_N) out[(size_t)s * L_N + n] = v;                                  // z_mu
      else         out[(size_t)B_N * L_N + (size_t)s * L_N + (n - L_N)] = v;      // z_logvar
    }
  }
}

extern "C" void kernel_launch(void* const* d_in, const int* in_sizes, int n_in,
                              void* d_out, int out_size, void* d_ws, size_t ws_size,
                              hipStream_t stream) {
  const float* x   = (const float*)d_in[0];
  const int*   idx = (const int*)d_in[1];
  const float* W1  = (const float*)d_in[2];
  const float* b1  = (const float*)d_in[3];
  const float* W2  = (const float*)d_in[4];
  const float* b2  = (const float*)d_in[5];
  float* out = (float*)d_out;

  // ws layout: [off_al: 32 ints][order: PAD_ROWS ints][h1buf: PAD_ROWS*H floats]
  int* off_al = (int*)d_ws;
  int* order  = off_al + 32;
  float* h1buf = (float*)(order + PAD_ROWS);   // byte offset 36992, 16B-aligned

  group_kernel<<<1, 256, 0, stream>>>(idx, off_al, order);
  gemm1_kernel<<<dim3(NTILES, 7), 256, 0, stream>>>(x, W1, b1, off_al, order, h1buf);
  gemm2_kernel<<<dim3(NTILES, 8), 256, 0, stream>>>(h1buf, W2, b2, off_al, order, out);
}